// Round 9
// baseline (326.120 us; speedup 1.0000x reference)
//
#include <hip/hip_runtime.h>

typedef unsigned short u16;
typedef unsigned int u32;
typedef short bf16x8 __attribute__((ext_vector_type(8)));
typedef float f32x4 __attribute__((ext_vector_type(4)));

#define AS1 __attribute__((address_space(1)))
#define AS3 __attribute__((address_space(3)))

#if __has_builtin(__builtin_amdgcn_exp2f)
#define EX2(x) __builtin_amdgcn_exp2f(x)
#else
#define EX2(x) exp2f(x)
#endif

__device__ __forceinline__ float bf2f(u16 u){ return __uint_as_float(((u32)u)<<16); }
__device__ __forceinline__ u16 f2bf(float f){
  u32 x = __float_as_uint(f);
  x += 0x7fffu + ((x>>16)&1u);   // round-to-nearest-even
  return (u16)(x>>16);
}
__device__ __forceinline__ float gelu_exact(float x){
  return 0.5f*x*(1.f + erff(x*0.7071067811865475f));
}

// ---------------- transpose + cast fp32 W[K][N] -> bf16 WT[N][K] ----------------
__global__ __launch_bounds__(256) void transpose_cast(
    const float* __restrict__ w, u16* __restrict__ wt, int K, int N)
{
  __shared__ float t[32][33];
  int lx = threadIdx.x & 31, ly = threadIdx.x >> 5;
  int n0 = blockIdx.x*32, k0 = blockIdx.y*32;
  #pragma unroll
  for (int j=0;j<4;j++) t[ly+j*8][lx] = w[(long)(k0+ly+j*8)*N + n0+lx];
  __syncthreads();
  #pragma unroll
  for (int j=0;j<4;j++) wt[(long)(n0+ly+j*8)*K + k0+lx] = f2bf(t[lx][ly+j*8]);
}

// ---------------- layernorm fp32 row(768) -> bf16 ----------------
__global__ __launch_bounds__(256) void ln_rows(
    const float* __restrict__ x, const float* __restrict__ w, u16* __restrict__ out)
{
  int row = blockIdx.x, tid = threadIdx.x;
  const float* xr = x + (long)row*768;
  float v0 = xr[tid], v1 = xr[tid+256], v2 = xr[tid+512];
  float s = v0+v1+v2, sq = v0*v0+v1*v1+v2*v2;
  #pragma unroll
  for (int o=32;o>=1;o>>=1){ s += __shfl_down(s,o); sq += __shfl_down(sq,o); }
  __shared__ float red[8];
  int wv = tid>>6, ln = tid&63;
  if (ln==0){ red[wv]=s; red[wv+4]=sq; }
  __syncthreads();
  float S  = red[0]+red[1]+red[2]+red[3];
  float SQ = red[4]+red[5]+red[6]+red[7];
  float mu = S*(1.f/768.f);
  float var = SQ*(1.f/768.f) - mu*mu;
  float rstd = rsqrtf(var + 1e-5f);
  u16* o = out + (long)row*768;
  o[tid]     = f2bf((v0-mu)*rstd*w[tid]);
  o[tid+256] = f2bf((v1-mu)*rstd*w[tid+256]);
  o[tid+512] = f2bf((v2-mu)*rstd*w[tid+512]);
}

// ---------------- fused: x2 = resid + p0 + p1 (write fp32) ; xln = LN(x2)*w (write bf16) ----------------
__global__ __launch_bounds__(256) void reduce2_ln(
    const float* __restrict__ p, const float* __restrict__ resid,
    const float* __restrict__ w, float* __restrict__ x2, u16* __restrict__ xln, long n)
{
  int row = blockIdx.x, tid = threadIdx.x;
  long off = (long)row*768;
  float v[3];
  #pragma unroll
  for (int j=0;j<3;j++){
    long i = off + tid + j*256;
    v[j] = resid[i] + p[i] + p[n+i];
    x2[i] = v[j];
  }
  float s = v[0]+v[1]+v[2], sq = v[0]*v[0]+v[1]*v[1]+v[2]*v[2];
  #pragma unroll
  for (int o=32;o>=1;o>>=1){ s += __shfl_down(s,o); sq += __shfl_down(sq,o); }
  __shared__ float red[8];
  int wv = tid>>6, ln = tid&63;
  if (ln==0){ red[wv]=s; red[wv+4]=sq; }
  __syncthreads();
  float S  = red[0]+red[1]+red[2]+red[3];
  float SQ = red[4]+red[5]+red[6]+red[7];
  float mu = S*(1.f/768.f);
  float var = SQ*(1.f/768.f) - mu*mu;
  float rstd = rsqrtf(var + 1e-5f);
  #pragma unroll
  for (int j=0;j<3;j++)
    xln[off + tid + j*256] = f2bf((v[j]-mu)*rstd*w[tid + j*256]);
}

// ---------------- transpose V slice of qkv -> vt[b][h][d][T] (bf16) ----------------
__global__ __launch_bounds__(256) void v_transpose(
    const u16* __restrict__ qkv, u16* __restrict__ vt)
{
  __shared__ __align__(16) u16 t[64*72];
  int b = blockIdx.z, h = blockIdx.y, t0 = blockIdx.x*64;
  int tid = threadIdx.x;
  int r = tid>>2, g = tid&3, c8 = g*16;
  const u16* src = qkv + ((long)(b*2048 + t0 + r))*2304 + 1536 + h*64 + c8;
  int wcol = c8 ^ (((r>>4)&3)*16);
  *(uint4*)&t[r*72 + wcol]     = *(const uint4*)src;
  *(uint4*)&t[r*72 + wcol + 8] = *(const uint4*)(src + 8);
  __syncthreads();
  int d = r;
  int rcol = d ^ (g*16);
  u32 pk[8];
  #pragma unroll
  for (int j=0;j<8;j++){
    u32 lo = t[(c8+2*j  )*72 + rcol];
    u32 hi = t[(c8+2*j+1)*72 + rcol];
    pk[j] = lo | (hi<<16);
  }
  u16* dst = vt + ((long)((b*12+h)*64 + d))*2048 + t0 + c8;
  uint4 o0 = {pk[0],pk[1],pk[2],pk[3]};
  uint4 o1 = {pk[4],pk[5],pk[6],pk[7]};
  *(uint4*)dst       = o0;
  *(uint4*)(dst + 8) = o1;
}

// ---------------- bf16 GEMM: 2-phase dbuf + counted vmcnt (T4), raw s_barrier ----------------
// EPI 0: bf16 + q2/k2; EPI 1: gelu->bf16   (unchanged from round 8)
template<int EPI>
__global__ __launch_bounds__(256) void gemm_bt(
    const u16* __restrict__ A, const u16* __restrict__ BT,
    int M, int N, int K,
    u16* __restrict__ outB,
    float* __restrict__ q2g, float* __restrict__ k2g)
{
  __shared__ __align__(16) u16 As[2][128*32];
  __shared__ __align__(16) u16 Bs[2][128*32];
  int tid = threadIdx.x;
  int gx = gridDim.x;
  int nwg = gx * gridDim.y;
  int flat = blockIdx.x + gx*blockIdx.y;
  int cpx = nwg >> 3;
  int swz = (flat & 7)*cpx + (flat >> 3);
  int n0 = (swz % gx)*128, m0 = (swz / gx)*128;
  int w = tid>>6, lane = tid&63, lr = lane&15, lg = lane>>4;
  int wr = w>>1, wc = w&1;
  f32x4 acc[4][4];
  f32x4 z = {0.f,0.f,0.f,0.f};
  #pragma unroll
  for (int m=0;m<4;m++)
    #pragma unroll
    for (int n=0;n<4;n++) acc[m][n] = z;
  int rr16 = lane>>2, cc = (lane&3)*8;
  const u16* gA0 = A  + (long)(m0 + (2*w  )*16 + rr16)*K + cc;
  const u16* gA1 = A  + (long)(m0 + (2*w+1)*16 + rr16)*K + cc;
  const u16* gB0 = BT + (long)(n0 + (2*w  )*16 + rr16)*K + cc;
  const u16* gB1 = BT + (long)(n0 + (2*w+1)*16 + rr16)*K + cc;
  int o0 = (2*w)*512, o1 = (2*w+1)*512;
  __builtin_amdgcn_global_load_lds((const AS1 void*)gA0, (AS3 void*)(&As[0][o0]), 16, 0, 0);
  __builtin_amdgcn_global_load_lds((const AS1 void*)gA1, (AS3 void*)(&As[0][o1]), 16, 0, 0);
  __builtin_amdgcn_global_load_lds((const AS1 void*)gB0, (AS3 void*)(&Bs[0][o0]), 16, 0, 0);
  __builtin_amdgcn_global_load_lds((const AS1 void*)gB1, (AS3 void*)(&Bs[0][o1]), 16, 0, 0);
  gA0 += 32; gA1 += 32; gB0 += 32; gB1 += 32;
  int cur = 0;
  for (int k0=0; k0<K; k0+=32){
    __builtin_amdgcn_s_barrier();
    if (k0+32 < K){
      int nx = cur^1;
      __builtin_amdgcn_global_load_lds((const AS1 void*)gA0, (AS3 void*)(&As[nx][o0]), 16, 0, 0);
      __builtin_amdgcn_global_load_lds((const AS1 void*)gA1, (AS3 void*)(&As[nx][o1]), 16, 0, 0);
      __builtin_amdgcn_global_load_lds((const AS1 void*)gB0, (AS3 void*)(&Bs[nx][o0]), 16, 0, 0);
      __builtin_amdgcn_global_load_lds((const AS1 void*)gB1, (AS3 void*)(&Bs[nx][o1]), 16, 0, 0);
      gA0 += 32; gA1 += 32; gB0 += 32; gB1 += 32;
      asm volatile("s_waitcnt vmcnt(4)" ::: "memory");
    } else {
      asm volatile("s_waitcnt vmcnt(0)" ::: "memory");
    }
    __builtin_amdgcn_sched_barrier(0);
    const u16* Ac = As[cur];
    const u16* Bc = Bs[cur];
    bf16x8 af[4], bfr[4];
    #pragma unroll
    for (int m=0;m<4;m++) af[m]  = *(const bf16x8*)&Ac[(wr*64+m*16+lr)*32 + lg*8];
    #pragma unroll
    for (int n=0;n<4;n++) bfr[n] = *(const bf16x8*)&Bc[(wc*64+n*16+lr)*32 + lg*8];
    #pragma unroll
    for (int m=0;m<4;m++)
      #pragma unroll
      for (int n=0;n<4;n++)
        acc[m][n] = __builtin_amdgcn_mfma_f32_16x16x32_bf16(af[m], bfr[n], acc[m][n], 0,0,0);
    cur ^= 1;
  }
  if (EPI==0){
    #pragma unroll
    for (int m=0;m<4;m++){
      float s2[4] = {0.f,0.f,0.f,0.f};
      #pragma unroll
      for (int n=0;n<4;n++)
        #pragma unroll
        for (int r=0;r<4;r++){
          int row = m0 + wr*64 + m*16 + lg*4 + r;
          int col = n0 + wc*64 + n*16 + lr;
          u16 ub = f2bf(acc[m][n][r]);
          outB[(long)row*N + col] = ub;
          float vr = bf2f(ub);
          s2[r] += vr*vr;
        }
      #pragma unroll
      for (int r=0;r<4;r++){
        float t = s2[r];
        t += __shfl_xor(t,1); t += __shfl_xor(t,2); t += __shfl_xor(t,4); t += __shfl_xor(t,8);
        if (lr==0){
          int head = (n0 + wc*64) >> 6;
          int row = m0 + wr*64 + m*16 + lg*4 + r;
          int bb = row >> 11, tt = row & 2047;
          if (head < 12)      q2g[((long)(bb*12 + head     ))*2048 + tt] = t;
          else if (head < 24) k2g[((long)(bb*12 + head - 12))*2048 + tt] = t;
        }
      }
    }
  } else {
    #pragma unroll
    for (int m=0;m<4;m++)
      #pragma unroll
      for (int n=0;n<4;n++)
        #pragma unroll
        for (int r=0;r<4;r++){
          int row = m0 + wr*64 + m*16 + lg*4 + r;
          int col = n0 + wc*64 + n*16 + lr;
          outB[(long)row*N + col] = f2bf(gelu_exact(acc[m][n][r]));
        }
  }
}

// ---------------- split-K GEMM (BM=128, BN=64), 2-phase dbuf + counted vmcnt ----------------
__global__ __launch_bounds__(256) void gemm_ks(
    const u16* __restrict__ A, const u16* __restrict__ BT,
    int M, int N, int K, int KS,
    float* __restrict__ pb)
{
  __shared__ __align__(16) u16 As[2][128*32];
  __shared__ __align__(16) u16 Bs[2][64*32];
  int tid = threadIdx.x;
  int n0 = blockIdx.x*64, m0 = blockIdx.y*128;
  int kbeg = blockIdx.z*KS;
  int w = tid>>6, lane = tid&63, lr = lane&15, lg = lane>>4;
  int wr = w>>1, wc = w&1;
  f32x4 acc[4][2];
  f32x4 z = {0.f,0.f,0.f,0.f};
  #pragma unroll
  for (int m=0;m<4;m++){ acc[m][0]=z; acc[m][1]=z; }
  int rr16 = lane>>2, cc = (lane&3)*8;
  const u16* gA0 = A  + (long)(m0 + (2*w  )*16 + rr16)*K + kbeg + cc;
  const u16* gA1 = A  + (long)(m0 + (2*w+1)*16 + rr16)*K + kbeg + cc;
  const u16* gB0 = BT + (long)(n0 + w*16 + rr16)*K + kbeg + cc;
  int oa0 = (2*w)*512, oa1 = (2*w+1)*512, ob = w*512;
  __builtin_amdgcn_global_load_lds((const AS1 void*)gA0, (AS3 void*)(&As[0][oa0]), 16, 0, 0);
  __builtin_amdgcn_global_load_lds((const AS1 void*)gA1, (AS3 void*)(&As[0][oa1]), 16, 0, 0);
  __builtin_amdgcn_global_load_lds((const AS1 void*)gB0, (AS3 void*)(&Bs[0][ob ]), 16, 0, 0);
  gA0 += 32; gA1 += 32; gB0 += 32;
  int cur = 0;
  for (int k0=0; k0<KS; k0+=32){
    __builtin_amdgcn_s_barrier();
    if (k0+32 < KS){
      int nx = cur^1;
      __builtin_amdgcn_global_load_lds((const AS1 void*)gA0, (AS3 void*)(&As[nx][oa0]), 16, 0, 0);
      __builtin_amdgcn_global_load_lds((const AS1 void*)gA1, (AS3 void*)(&As[nx][oa1]), 16, 0, 0);
      __builtin_amdgcn_global_load_lds((const AS1 void*)gB0, (AS3 void*)(&Bs[nx][ob ]), 16, 0, 0);
      gA0 += 32; gA1 += 32; gB0 += 32;
      asm volatile("s_waitcnt vmcnt(3)" ::: "memory");
    } else {
      asm volatile("s_waitcnt vmcnt(0)" ::: "memory");
    }
    __builtin_amdgcn_sched_barrier(0);
    const u16* Ac = As[cur];
    const u16* Bc = Bs[cur];
    bf16x8 af[4], bfr[2];
    #pragma unroll
    for (int m=0;m<4;m++) af[m]  = *(const bf16x8*)&Ac[(wr*64+m*16+lr)*32 + lg*8];
    #pragma unroll
    for (int n=0;n<2;n++) bfr[n] = *(const bf16x8*)&Bc[(wc*32+n*16+lr)*32 + lg*8];
    #pragma unroll
    for (int m=0;m<4;m++)
      #pragma unroll
      for (int n=0;n<2;n++)
        acc[m][n] = __builtin_amdgcn_mfma_f32_16x16x32_bf16(af[m], bfr[n], acc[m][n], 0,0,0);
    cur ^= 1;
  }
  long zofs = (long)blockIdx.z*M*N;
  #pragma unroll
  for (int m=0;m<4;m++)
    #pragma unroll
    for (int n=0;n<2;n++)
      #pragma unroll
      for (int r=0;r<4;r++){
        int row = m0 + wr*64 + m*16 + lg*4 + r;
        int col = n0 + wc*32 + n*16 + lr;
        pb[zofs + (long)row*N + col] = acc[m][n][r];
      }
}

// ---------------- out = resid + p0 + p1 (f32) ----------------
__global__ __launch_bounds__(256) void reduce2(
    const float* __restrict__ p, const float* __restrict__ resid,
    float* __restrict__ out, long n)
{
  long i = ((long)blockIdx.x*256 + threadIdx.x)*4;
  f32x4 a = *(const f32x4*)(resid+i);
  f32x4 b = *(const f32x4*)(p+i);
  f32x4 c = *(const f32x4*)(p+n+i);
  *(f32x4*)(out+i) = a+b+c;
}

// ---------------- fused causal exp(-sqL2/16) attention ----------------
// 1536 blocks x 2 waves; block = ONE 32-q-row subtile s (long-first dispatch, backfill balances).
// K LDS-staged (dbuf); V^T read DIRECT from global (L2-resident), issued early each tile.
__global__ __launch_bounds__(128) void attn_fused(
    const u16* __restrict__ qkv, const u16* __restrict__ vt,
    const float* __restrict__ q2g, const float* __restrict__ k2g,
    u16* __restrict__ Y)
{
  constexpr int C3=2304, C=768, T=2048, PADP=72;
  constexpr float C1 = 0.18033688f;   // 0.125 * log2(e)
  constexpr float S2 = 0.09016844f;   // 0.0625 * log2(e)
  __shared__ __align__(16) u16 Ks[2][4096];
  __shared__ __align__(16) u16 Ps[2][16*PADP];
  int bz = blockIdx.x;
  int swzb = (bz&7)*192 + (bz>>3);    // XCD-chunked (1536 = 8*192): 3 heads per XCD-L2
  int s  = 63 - (swzb & 63);          // long subtiles dispatched first
  int hh = (swzb>>6) % 12;
  int b  = swzb / 768;
  int tid = threadIdx.x, w = tid>>6, lane = tid&63, lr = lane&15, lg = lane>>4;
  long base = (long)b*T;
  long bh = (long)(b*12 + hh);
  const u16* kbase = qkv + base*C3 + C + hh*64;
  const u16* vbase = vt + bh*64*(long)T;
  const float* k2p = k2g + bh*T;
  const float* q2p0 = q2g + bh*T;

  // K staging addresses: linear LDS dest, inverse-swizzled global source
  int rowl = lane>>3;
  int c16 = (lane&7) ^ rowl;
  const u16* kp[4];
  #pragma unroll
  for (int i=0;i<4;i++){
    int c = w*4 + i;
    kp[i] = kbase + (long)(c*8 + rowl)*C3 + c16*8;
  }
  u16* Pw = &Ps[w][0];
  f32x4 z = {0.f,0.f,0.f,0.f};

  int ktl = s>>1;
  int qg0 = s*32 + w*16;
  const u16* qrow = qkv + (base + qg0 + lr)*C3 + hh*64;
  bf16x8 aq0 = *(const bf16x8*)(qrow + lg*8);
  bf16x8 aq1 = *(const bf16x8*)(qrow + 32 + lg*8);
  const float q2v = S2 * q2p0[qg0 + lr];   // this lane's q-column (swapped layout)
  const int qg_s = qg0 + lr;
  f32x4 accY[4];
  #pragma unroll
  for (int i=0;i<4;i++) accY[i] = z;

  // prologue: stage K tile 0
  #pragma unroll
  for (int i=0;i<4;i++)
    __builtin_amdgcn_global_load_lds((const AS1 void*)kp[i], (AS3 void*)&Ks[0][(w*4+i)*512], 16, 0, 0);
  f32x4 k2n4[4];
  #pragma unroll
  for (int nf=0;nf<4;nf++){
    f32x4 t4 = *(const f32x4*)&k2p[nf*16 + lg*4];
    k2n4[nf] = t4 * S2;
  }
  __syncthreads();

  int cur = 0;
  for (int kt=0; kt<=ktl; ++kt){
    int kg0 = kt*64;
    f32x4 k2c4[4];
    #pragma unroll
    for (int i=0;i<4;i++) k2c4[i] = k2n4[i];
    // V^T direct loads for THIS tile (L2-resident; ~600cy before PV use)
    uint4 vr[8];
    #pragma unroll
    for (int nf=0;nf<4;nf++){
      const u16* vpn = vbase + (long)(nf*16 + lr)*T + kg0 + lg*8;
      vr[2*nf  ] = *(const uint4*)(vpn);
      vr[2*nf+1] = *(const uint4*)(vpn + 32);
    }
    if (kt < ktl){                     // prefetch next K tile
      long kadd = (long)(kt+1)*64*C3;
      #pragma unroll
      for (int i=0;i<4;i++)
        __builtin_amdgcn_global_load_lds((const AS1 void*)(kp[i]+kadd), (AS3 void*)&Ks[cur^1][(w*4+i)*512], 16, 0, 0);
      #pragma unroll
      for (int nf=0;nf<4;nf++){
        f32x4 t4 = *(const f32x4*)&k2p[(kt+1)*64 + nf*16 + lg*4];
        k2n4[nf] = t4 * S2;
      }
    }
    const u16* Kc = &Ks[cur][0];
    #pragma unroll
    for (int nf=0;nf<4;nf++){
      int row = nf*16 + lr;
      int sw0 = ((lg    ) ^ (row&7))*8;
      int sw1 = ((4 | lg) ^ (row&7))*8;
      bf16x8 kb0 = *(const bf16x8*)&Kc[row*64 + sw0];
      bf16x8 kb1 = *(const bf16x8*)&Kc[row*64 + sw1];
      f32x4 sc = z;
      sc = __builtin_amdgcn_mfma_f32_16x16x32_bf16(kb0, aq0, sc, 0,0,0);  // swapped: D[k][q]
      sc = __builtin_amdgcn_mfma_f32_16x16x32_bf16(kb1, aq1, sc, 0,0,0);
      int kb = kg0 + nf*16 + lg*4;
      u16 pbk[4];
      #pragma unroll
      for (int rr=0;rr<4;rr++){
        float arg = sc[rr]*C1 - q2v - k2c4[nf][rr];
        float e = EX2(arg);
        e = (kb + rr <= qg_s) ? e : 0.f;
        pbk[rr] = f2bf(e);
      }
      uint2 pk2;
      pk2.x = (u32)pbk[0] | ((u32)pbk[1]<<16);
      pk2.y = (u32)pbk[2] | ((u32)pbk[3]<<16);
      *(uint2*)&Pw[lr*PADP + nf*16 + lg*4] = pk2;   // P[q=lr][k], 8B aligned
    }
    __builtin_amdgcn_wave_barrier();
    asm volatile("s_waitcnt lgkmcnt(0)" ::: "memory");
    bf16x8 ap0 = *(const bf16x8*)&Pw[lr*PADP + lg*8];
    bf16x8 ap1 = *(const bf16x8*)&Pw[lr*PADP + 32 + lg*8];
    #pragma unroll
    for (int nf=0;nf<4;nf++){
      accY[nf] = __builtin_amdgcn_mfma_f32_16x16x32_bf16(ap0, *(const bf16x8*)&vr[2*nf  ], accY[nf], 0,0,0);
      accY[nf] = __builtin_amdgcn_mfma_f32_16x16x32_bf16(ap1, *(const bf16x8*)&vr[2*nf+1], accY[nf], 0,0,0);
    }
    __syncthreads();                   // guards Ks buffer reuse (2 waves share Ks)
    cur ^= 1;
  }
  #pragma unroll
  for (int nf=0;nf<4;nf++)
    #pragma unroll
    for (int rr=0;rr<4;rr++)
      Y[(base + qg0 + lg*4 + rr)*C + hh*64 + nf*16 + lr] = f2bf(accY[nf][rr]);
}

extern "C" void kernel_launch(void* const* d_in, const int* in_sizes, int n_in,
                              void* d_out, int out_size, void* d_ws, size_t ws_size,
                              hipStream_t stream)
{
  (void)in_sizes; (void)n_in; (void)out_size; (void)ws_size;
  const float* x      = (const float*)d_in[0];
  const float* w_ln1  = (const float*)d_in[1];
  const float* w_attn = (const float*)d_in[2];
  const float* w_ap   = (const float*)d_in[3];
  const float* w_ln2  = (const float*)d_in[4];
  const float* w_fc   = (const float*)d_in[5];
  const float* w_mlp  = (const float*)d_in[6];
  float* out = (float*)d_out;
  const int M = 4096, T = 2048;   // B=2, T=2048, C=768
  const long NROW = (long)M*768;

  u16* ws      = (u16*)d_ws;
  u16* wT_attn = ws;                        // 2304*768
  u16* wT_ap   = wT_attn + 2304*768;        // 768*768
  u16* wT_fc   = wT_ap   + 768*768;         // 3072*768
  u16* wT_mlp  = wT_fc   + 3072*768;        // 768*3072
  u16* xln     = wT_mlp  + 768*3072;        // 4096*768
  u16* qkvb    = xln     + 4096*768;        // 4096*2304
  u16* Ybuf    = qkvb    + 4096*2304;       // 4096*768
  u16* hbuf    = qkvb;                      // 4096*3072 aliases qkv|Ybuf (exact fit)
  float* x2    = (float*)(Ybuf + 4096*768); // 4096*768 fp32
  u16* vtb     = (u16*)(x2 + 4096*768);     // 2*12*64*2048
  float* q2g   = (float*)(vtb + 2*12*64*2048); // 24*2048
  float* k2g   = q2g + 24*2048;                // 24*2048
  float* pbuf  = k2g + 24*2048;                // 2 * 4096*768 fp32 (split-K partials)

  dim3 blk(256);
  transpose_cast<<<dim3(2304/32,  768/32), blk, 0, stream>>>(w_attn, wT_attn,  768, 2304);
  transpose_cast<<<dim3( 768/32,  768/32), blk, 0, stream>>>(w_ap,   wT_ap,    768,  768);
  transpose_cast<<<dim3(3072/32,  768/32), blk, 0, stream>>>(w_fc,   wT_fc,    768, 3072);
  transpose_cast<<<dim3( 768/32, 3072/32), blk, 0, stream>>>(w_mlp,  wT_mlp,  3072,  768);

  ln_rows<<<dim3(M), blk, 0, stream>>>(x, w_ln1, xln);
  gemm_bt<0><<<dim3(2304/128, M/128), blk, 0, stream>>>(xln, wT_attn, M, 2304, 768, qkvb, q2g, k2g);
  v_transpose<<<dim3(T/64, 12, 2), blk, 0, stream>>>(qkvb, vtb);
  attn_fused<<<dim3(2*12*64), dim3(128), 0, stream>>>(qkvb, vtb, q2g, k2g, Ybuf);
  gemm_ks<<<dim3(768/64, M/128, 2), blk, 0, stream>>>(Ybuf, wT_ap, M, 768, 768, 384, pbuf);
  reduce2_ln<<<dim3(M), blk, 0, stream>>>(pbuf, x, w_ln2, x2, xln, NROW);
  gemm_bt<1><<<dim3(3072/128, M/128), blk, 0, stream>>>(xln, wT_fc, M, 3072, 768, hbuf, nullptr, nullptr);
  gemm_ks<<<dim3(768/64, M/128, 2), blk, 0, stream>>>(hbuf, wT_mlp, M, 768, 3072, 1536, pbuf);
  reduce2<<<dim3(NROW/1024), blk, 0, stream>>>(pbuf, x2, out, NROW);
}

// Round 10
// 291.229 us; speedup vs baseline: 1.1198x; 1.1198x over previous
//
#include <hip/hip_runtime.h>

typedef unsigned short u16;
typedef unsigned int u32;
typedef short bf16x8 __attribute__((ext_vector_type(8)));
typedef float f32x4 __attribute__((ext_vector_type(4)));

#define AS1 __attribute__((address_space(1)))
#define AS3 __attribute__((address_space(3)))

#if __has_builtin(__builtin_amdgcn_exp2f)
#define EX2(x) __builtin_amdgcn_exp2f(x)
#else
#define EX2(x) exp2f(x)
#endif

__device__ __forceinline__ float bf2f(u16 u){ return __uint_as_float(((u32)u)<<16); }
__device__ __forceinline__ u16 f2bf(float f){
  u32 x = __float_as_uint(f);
  x += 0x7fffu + ((x>>16)&1u);   // round-to-nearest-even
  return (u16)(x>>16);
}
__device__ __forceinline__ float gelu_exact(float x){
  return 0.5f*x*(1.f + erff(x*0.7071067811865475f));
}

// ---------------- transpose + cast fp32 W[K][N] -> bf16 WT[N][K] ----------------
__global__ __launch_bounds__(256) void transpose_cast(
    const float* __restrict__ w, u16* __restrict__ wt, int K, int N)
{
  __shared__ float t[32][33];
  int lx = threadIdx.x & 31, ly = threadIdx.x >> 5;
  int n0 = blockIdx.x*32, k0 = blockIdx.y*32;
  #pragma unroll
  for (int j=0;j<4;j++) t[ly+j*8][lx] = w[(long)(k0+ly+j*8)*N + n0+lx];
  __syncthreads();
  #pragma unroll
  for (int j=0;j<4;j++) wt[(long)(n0+ly+j*8)*K + k0+lx] = f2bf(t[lx][ly+j*8]);
}

// ---------------- layernorm fp32 row(768) -> bf16 ----------------
__global__ __launch_bounds__(256) void ln_rows(
    const float* __restrict__ x, const float* __restrict__ w, u16* __restrict__ out)
{
  int row = blockIdx.x, tid = threadIdx.x;
  const float* xr = x + (long)row*768;
  float v0 = xr[tid], v1 = xr[tid+256], v2 = xr[tid+512];
  float s = v0+v1+v2, sq = v0*v0+v1*v1+v2*v2;
  #pragma unroll
  for (int o=32;o>=1;o>>=1){ s += __shfl_down(s,o); sq += __shfl_down(sq,o); }
  __shared__ float red[8];
  int wv = tid>>6, ln = tid&63;
  if (ln==0){ red[wv]=s; red[wv+4]=sq; }
  __syncthreads();
  float S  = red[0]+red[1]+red[2]+red[3];
  float SQ = red[4]+red[5]+red[6]+red[7];
  float mu = S*(1.f/768.f);
  float var = SQ*(1.f/768.f) - mu*mu;
  float rstd = rsqrtf(var + 1e-5f);
  u16* o = out + (long)row*768;
  o[tid]     = f2bf((v0-mu)*rstd*w[tid]);
  o[tid+256] = f2bf((v1-mu)*rstd*w[tid+256]);
  o[tid+512] = f2bf((v2-mu)*rstd*w[tid+512]);
}

// ---------------- fused: x2 = resid + p0 + p1 (write fp32) ; xln = LN(x2)*w (write bf16) ----------------
__global__ __launch_bounds__(256) void reduce2_ln(
    const float* __restrict__ p, const float* __restrict__ resid,
    const float* __restrict__ w, float* __restrict__ x2, u16* __restrict__ xln, long n)
{
  int row = blockIdx.x, tid = threadIdx.x;
  long off = (long)row*768;
  float v[3];
  #pragma unroll
  for (int j=0;j<3;j++){
    long i = off + tid + j*256;
    v[j] = resid[i] + p[i] + p[n+i];
    x2[i] = v[j];
  }
  float s = v[0]+v[1]+v[2], sq = v[0]*v[0]+v[1]*v[1]+v[2]*v[2];
  #pragma unroll
  for (int o=32;o>=1;o>>=1){ s += __shfl_down(s,o); sq += __shfl_down(sq,o); }
  __shared__ float red[8];
  int wv = tid>>6, ln = tid&63;
  if (ln==0){ red[wv]=s; red[wv+4]=sq; }
  __syncthreads();
  float S  = red[0]+red[1]+red[2]+red[3];
  float SQ = red[4]+red[5]+red[6]+red[7];
  float mu = S*(1.f/768.f);
  float var = SQ*(1.f/768.f) - mu*mu;
  float rstd = rsqrtf(var + 1e-5f);
  #pragma unroll
  for (int j=0;j<3;j++)
    xln[off + tid + j*256] = f2bf((v[j]-mu)*rstd*w[tid + j*256]);
}

// ---------------- transpose V slice of qkv -> vt[b][h][d][T] (bf16) ----------------
__global__ __launch_bounds__(256) void v_transpose(
    const u16* __restrict__ qkv, u16* __restrict__ vt)
{
  __shared__ __align__(16) u16 t[64*72];
  int b = blockIdx.z, h = blockIdx.y, t0 = blockIdx.x*64;
  int tid = threadIdx.x;
  int r = tid>>2, g = tid&3, c8 = g*16;
  const u16* src = qkv + ((long)(b*2048 + t0 + r))*2304 + 1536 + h*64 + c8;
  int wcol = c8 ^ (((r>>4)&3)*16);
  *(uint4*)&t[r*72 + wcol]     = *(const uint4*)src;
  *(uint4*)&t[r*72 + wcol + 8] = *(const uint4*)(src + 8);
  __syncthreads();
  int d = r;
  int rcol = d ^ (g*16);
  u32 pk[8];
  #pragma unroll
  for (int j=0;j<8;j++){
    u32 lo = t[(c8+2*j  )*72 + rcol];
    u32 hi = t[(c8+2*j+1)*72 + rcol];
    pk[j] = lo | (hi<<16);
  }
  u16* dst = vt + ((long)((b*12+h)*64 + d))*2048 + t0 + c8;
  uint4 o0 = {pk[0],pk[1],pk[2],pk[3]};
  uint4 o1 = {pk[4],pk[5],pk[6],pk[7]};
  *(uint4*)dst       = o0;
  *(uint4*)(dst + 8) = o1;
}

// ---------------- bf16 GEMM: 2-phase dbuf + counted vmcnt (T4), raw s_barrier ----------------
// EPI 0: bf16 + q2/k2; EPI 1: gelu->bf16   (unchanged from round 8)
template<int EPI>
__global__ __launch_bounds__(256) void gemm_bt(
    const u16* __restrict__ A, const u16* __restrict__ BT,
    int M, int N, int K,
    u16* __restrict__ outB,
    float* __restrict__ q2g, float* __restrict__ k2g)
{
  __shared__ __align__(16) u16 As[2][128*32];
  __shared__ __align__(16) u16 Bs[2][128*32];
  int tid = threadIdx.x;
  int gx = gridDim.x;
  int nwg = gx * gridDim.y;
  int flat = blockIdx.x + gx*blockIdx.y;
  int cpx = nwg >> 3;
  int swz = (flat & 7)*cpx + (flat >> 3);
  int n0 = (swz % gx)*128, m0 = (swz / gx)*128;
  int w = tid>>6, lane = tid&63, lr = lane&15, lg = lane>>4;
  int wr = w>>1, wc = w&1;
  f32x4 acc[4][4];
  f32x4 z = {0.f,0.f,0.f,0.f};
  #pragma unroll
  for (int m=0;m<4;m++)
    #pragma unroll
    for (int n=0;n<4;n++) acc[m][n] = z;
  int rr16 = lane>>2, cc = (lane&3)*8;
  const u16* gA0 = A  + (long)(m0 + (2*w  )*16 + rr16)*K + cc;
  const u16* gA1 = A  + (long)(m0 + (2*w+1)*16 + rr16)*K + cc;
  const u16* gB0 = BT + (long)(n0 + (2*w  )*16 + rr16)*K + cc;
  const u16* gB1 = BT + (long)(n0 + (2*w+1)*16 + rr16)*K + cc;
  int o0 = (2*w)*512, o1 = (2*w+1)*512;
  __builtin_amdgcn_global_load_lds((const AS1 void*)gA0, (AS3 void*)(&As[0][o0]), 16, 0, 0);
  __builtin_amdgcn_global_load_lds((const AS1 void*)gA1, (AS3 void*)(&As[0][o1]), 16, 0, 0);
  __builtin_amdgcn_global_load_lds((const AS1 void*)gB0, (AS3 void*)(&Bs[0][o0]), 16, 0, 0);
  __builtin_amdgcn_global_load_lds((const AS1 void*)gB1, (AS3 void*)(&Bs[0][o1]), 16, 0, 0);
  gA0 += 32; gA1 += 32; gB0 += 32; gB1 += 32;
  int cur = 0;
  for (int k0=0; k0<K; k0+=32){
    __builtin_amdgcn_s_barrier();
    if (k0+32 < K){
      int nx = cur^1;
      __builtin_amdgcn_global_load_lds((const AS1 void*)gA0, (AS3 void*)(&As[nx][o0]), 16, 0, 0);
      __builtin_amdgcn_global_load_lds((const AS1 void*)gA1, (AS3 void*)(&As[nx][o1]), 16, 0, 0);
      __builtin_amdgcn_global_load_lds((const AS1 void*)gB0, (AS3 void*)(&Bs[nx][o0]), 16, 0, 0);
      __builtin_amdgcn_global_load_lds((const AS1 void*)gB1, (AS3 void*)(&Bs[nx][o1]), 16, 0, 0);
      gA0 += 32; gA1 += 32; gB0 += 32; gB1 += 32;
      asm volatile("s_waitcnt vmcnt(4)" ::: "memory");
    } else {
      asm volatile("s_waitcnt vmcnt(0)" ::: "memory");
    }
    __builtin_amdgcn_sched_barrier(0);
    const u16* Ac = As[cur];
    const u16* Bc = Bs[cur];
    bf16x8 af[4], bfr[4];
    #pragma unroll
    for (int m=0;m<4;m++) af[m]  = *(const bf16x8*)&Ac[(wr*64+m*16+lr)*32 + lg*8];
    #pragma unroll
    for (int n=0;n<4;n++) bfr[n] = *(const bf16x8*)&Bc[(wc*64+n*16+lr)*32 + lg*8];
    #pragma unroll
    for (int m=0;m<4;m++)
      #pragma unroll
      for (int n=0;n<4;n++)
        acc[m][n] = __builtin_amdgcn_mfma_f32_16x16x32_bf16(af[m], bfr[n], acc[m][n], 0,0,0);
    cur ^= 1;
  }
  if (EPI==0){
    #pragma unroll
    for (int m=0;m<4;m++){
      float s2[4] = {0.f,0.f,0.f,0.f};
      #pragma unroll
      for (int n=0;n<4;n++)
        #pragma unroll
        for (int r=0;r<4;r++){
          int row = m0 + wr*64 + m*16 + lg*4 + r;
          int col = n0 + wc*64 + n*16 + lr;
          u16 ub = f2bf(acc[m][n][r]);
          outB[(long)row*N + col] = ub;
          float vr = bf2f(ub);
          s2[r] += vr*vr;
        }
      #pragma unroll
      for (int r=0;r<4;r++){
        float t = s2[r];
        t += __shfl_xor(t,1); t += __shfl_xor(t,2); t += __shfl_xor(t,4); t += __shfl_xor(t,8);
        if (lr==0){
          int head = (n0 + wc*64) >> 6;
          int row = m0 + wr*64 + m*16 + lg*4 + r;
          int bb = row >> 11, tt = row & 2047;
          if (head < 12)      q2g[((long)(bb*12 + head     ))*2048 + tt] = t;
          else if (head < 24) k2g[((long)(bb*12 + head - 12))*2048 + tt] = t;
        }
      }
    }
  } else {
    #pragma unroll
    for (int m=0;m<4;m++)
      #pragma unroll
      for (int n=0;n<4;n++)
        #pragma unroll
        for (int r=0;r<4;r++){
          int row = m0 + wr*64 + m*16 + lg*4 + r;
          int col = n0 + wc*64 + n*16 + lr;
          outB[(long)row*N + col] = f2bf(gelu_exact(acc[m][n][r]));
        }
  }
}

// ---------------- split-K GEMM (BM=128, BN=64), 2-phase dbuf + counted vmcnt ----------------
__global__ __launch_bounds__(256) void gemm_ks(
    const u16* __restrict__ A, const u16* __restrict__ BT,
    int M, int N, int K, int KS,
    float* __restrict__ pb)
{
  __shared__ __align__(16) u16 As[2][128*32];
  __shared__ __align__(16) u16 Bs[2][64*32];
  int tid = threadIdx.x;
  int n0 = blockIdx.x*64, m0 = blockIdx.y*128;
  int kbeg = blockIdx.z*KS;
  int w = tid>>6, lane = tid&63, lr = lane&15, lg = lane>>4;
  int wr = w>>1, wc = w&1;
  f32x4 acc[4][2];
  f32x4 z = {0.f,0.f,0.f,0.f};
  #pragma unroll
  for (int m=0;m<4;m++){ acc[m][0]=z; acc[m][1]=z; }
  int rr16 = lane>>2, cc = (lane&3)*8;
  const u16* gA0 = A  + (long)(m0 + (2*w  )*16 + rr16)*K + kbeg + cc;
  const u16* gA1 = A  + (long)(m0 + (2*w+1)*16 + rr16)*K + kbeg + cc;
  const u16* gB0 = BT + (long)(n0 + w*16 + rr16)*K + kbeg + cc;
  int oa0 = (2*w)*512, oa1 = (2*w+1)*512, ob = w*512;
  __builtin_amdgcn_global_load_lds((const AS1 void*)gA0, (AS3 void*)(&As[0][oa0]), 16, 0, 0);
  __builtin_amdgcn_global_load_lds((const AS1 void*)gA1, (AS3 void*)(&As[0][oa1]), 16, 0, 0);
  __builtin_amdgcn_global_load_lds((const AS1 void*)gB0, (AS3 void*)(&Bs[0][ob ]), 16, 0, 0);
  gA0 += 32; gA1 += 32; gB0 += 32;
  int cur = 0;
  for (int k0=0; k0<KS; k0+=32){
    __builtin_amdgcn_s_barrier();
    if (k0+32 < KS){
      int nx = cur^1;
      __builtin_amdgcn_global_load_lds((const AS1 void*)gA0, (AS3 void*)(&As[nx][oa0]), 16, 0, 0);
      __builtin_amdgcn_global_load_lds((const AS1 void*)gA1, (AS3 void*)(&As[nx][oa1]), 16, 0, 0);
      __builtin_amdgcn_global_load_lds((const AS1 void*)gB0, (AS3 void*)(&Bs[nx][ob ]), 16, 0, 0);
      gA0 += 32; gA1 += 32; gB0 += 32;
      asm volatile("s_waitcnt vmcnt(3)" ::: "memory");
    } else {
      asm volatile("s_waitcnt vmcnt(0)" ::: "memory");
    }
    __builtin_amdgcn_sched_barrier(0);
    const u16* Ac = As[cur];
    const u16* Bc = Bs[cur];
    bf16x8 af[4], bfr[2];
    #pragma unroll
    for (int m=0;m<4;m++) af[m]  = *(const bf16x8*)&Ac[(wr*64+m*16+lr)*32 + lg*8];
    #pragma unroll
    for (int n=0;n<2;n++) bfr[n] = *(const bf16x8*)&Bc[(wc*32+n*16+lr)*32 + lg*8];
    #pragma unroll
    for (int m=0;m<4;m++)
      #pragma unroll
      for (int n=0;n<2;n++)
        acc[m][n] = __builtin_amdgcn_mfma_f32_16x16x32_bf16(af[m], bfr[n], acc[m][n], 0,0,0);
    cur ^= 1;
  }
  long zofs = (long)blockIdx.z*M*N;
  #pragma unroll
  for (int m=0;m<4;m++)
    #pragma unroll
    for (int n=0;n<2;n++)
      #pragma unroll
      for (int r=0;r<4;r++){
        int row = m0 + wr*64 + m*16 + lg*4 + r;
        int col = n0 + wc*32 + n*16 + lr;
        pb[zofs + (long)row*N + col] = acc[m][n][r];
      }
}

// ---------------- out = resid + p0 + p1 (f32) ----------------
__global__ __launch_bounds__(256) void reduce2(
    const float* __restrict__ p, const float* __restrict__ resid,
    float* __restrict__ out, long n)
{
  long i = ((long)blockIdx.x*256 + threadIdx.x)*4;
  f32x4 a = *(const f32x4*)(resid+i);
  f32x4 b = *(const f32x4*)(p+i);
  f32x4 c = *(const f32x4*)(p+n+i);
  *(f32x4*)(out+i) = a+b+c;
}

// ---------------- fused causal exp(-sqL2/16) attention ----------------
// R8 structure (K AND V LDS-staged, dbuf) but UNPAIRED: 1536 blocks x 2 waves, one 32-q-row
// subtile each, long-first dispatch. + s_setprio around the compute cluster (T5).
__global__ __launch_bounds__(128) void attn_fused(
    const u16* __restrict__ qkv, const u16* __restrict__ vt,
    const float* __restrict__ q2g, const float* __restrict__ k2g,
    u16* __restrict__ Y)
{
  constexpr int C3=2304, C=768, T=2048, PADP=72;
  constexpr float C1 = 0.18033688f;   // 0.125 * log2(e)
  constexpr float S2 = 0.09016844f;   // 0.0625 * log2(e)
  __shared__ __align__(16) u16 Ks[2][4096];
  __shared__ __align__(16) u16 Vs[2][4096];
  __shared__ __align__(16) u16 Ps[2][16*PADP];
  int bz = blockIdx.x;
  int swzb = (bz&7)*192 + (bz>>3);    // XCD-chunked (1536 = 8*192): 3 heads per XCD-L2
  int s  = 63 - (swzb & 63);          // long subtiles dispatched first
  int hh = (swzb>>6) % 12;
  int b  = swzb / 768;
  int tid = threadIdx.x, w = tid>>6, lane = tid&63, lr = lane&15, lg = lane>>4;
  long base = (long)b*T;
  long bh = (long)(b*12 + hh);
  const u16* kbase = qkv + base*C3 + C + hh*64;
  const u16* vbase = vt + bh*64*(long)T;
  const float* k2p = k2g + bh*T;
  const float* q2p0 = q2g + bh*T;

  // staging addresses: linear LDS dest, inverse-swizzled global source
  int rowl = lane>>3;
  int c16 = (lane&7) ^ rowl;
  const u16* kp[4]; const u16* vp[4];
  #pragma unroll
  for (int i=0;i<4;i++){
    int c = w*4 + i;
    kp[i] = kbase + (long)(c*8 + rowl)*C3 + c16*8;
    vp[i] = vbase + (long)(c*8 + rowl)*T + c16*8;
  }
  u16* Pw = &Ps[w][0];
  f32x4 z = {0.f,0.f,0.f,0.f};

  int ktl = s>>1;
  int qg0 = s*32 + w*16;
  const u16* qrow = qkv + (base + qg0 + lr)*C3 + hh*64;
  bf16x8 aq0 = *(const bf16x8*)(qrow + lg*8);
  bf16x8 aq1 = *(const bf16x8*)(qrow + 32 + lg*8);
  const float q2v = S2 * q2p0[qg0 + lr];   // this lane's q-column (swapped layout)
  const int qg_s = qg0 + lr;
  f32x4 accY[4];
  #pragma unroll
  for (int i=0;i<4;i++) accY[i] = z;

  // prologue: stage K+V tile 0
  #pragma unroll
  for (int i=0;i<4;i++){
    __builtin_amdgcn_global_load_lds((const AS1 void*)kp[i], (AS3 void*)&Ks[0][(w*4+i)*512], 16, 0, 0);
    __builtin_amdgcn_global_load_lds((const AS1 void*)vp[i], (AS3 void*)&Vs[0][(w*4+i)*512], 16, 0, 0);
  }
  f32x4 k2n4[4];
  #pragma unroll
  for (int nf=0;nf<4;nf++){
    f32x4 t4 = *(const f32x4*)&k2p[nf*16 + lg*4];
    k2n4[nf] = t4 * S2;
  }
  __syncthreads();

  int cur = 0;
  for (int kt=0; kt<=ktl; ++kt){
    int kg0 = kt*64;
    f32x4 k2c4[4];
    #pragma unroll
    for (int i=0;i<4;i++) k2c4[i] = k2n4[i];
    if (kt < ktl){                     // prefetch next K+V tile into other buffer
      long kadd = (long)(kt+1)*64*C3;
      long vadd = (long)(kt+1)*64;
      #pragma unroll
      for (int i=0;i<4;i++){
        __builtin_amdgcn_global_load_lds((const AS1 void*)(kp[i]+kadd), (AS3 void*)&Ks[cur^1][(w*4+i)*512], 16, 0, 0);
        __builtin_amdgcn_global_load_lds((const AS1 void*)(vp[i]+vadd), (AS3 void*)&Vs[cur^1][(w*4+i)*512], 16, 0, 0);
      }
      #pragma unroll
      for (int nf=0;nf<4;nf++){
        f32x4 t4 = *(const f32x4*)&k2p[(kt+1)*64 + nf*16 + lg*4];
        k2n4[nf] = t4 * S2;
      }
    }
    const u16* Kc = &Ks[cur][0];
    const u16* Vc = &Vs[cur][0];
    __builtin_amdgcn_s_setprio(1);
    #pragma unroll
    for (int nf=0;nf<4;nf++){
      int row = nf*16 + lr;
      int sw0 = ((lg    ) ^ (row&7))*8;
      int sw1 = ((4 | lg) ^ (row&7))*8;
      bf16x8 kb0 = *(const bf16x8*)&Kc[row*64 + sw0];
      bf16x8 kb1 = *(const bf16x8*)&Kc[row*64 + sw1];
      f32x4 sc = z;
      sc = __builtin_amdgcn_mfma_f32_16x16x32_bf16(kb0, aq0, sc, 0,0,0);  // swapped: D[k][q]
      sc = __builtin_amdgcn_mfma_f32_16x16x32_bf16(kb1, aq1, sc, 0,0,0);
      int kb = kg0 + nf*16 + lg*4;
      u16 pbk[4];
      #pragma unroll
      for (int rr=0;rr<4;rr++){
        float arg = sc[rr]*C1 - q2v - k2c4[nf][rr];
        float e = EX2(arg);
        e = (kb + rr <= qg_s) ? e : 0.f;
        pbk[rr] = f2bf(e);
      }
      uint2 pk2;
      pk2.x = (u32)pbk[0] | ((u32)pbk[1]<<16);
      pk2.y = (u32)pbk[2] | ((u32)pbk[3]<<16);
      *(uint2*)&Pw[lr*PADP + nf*16 + lg*4] = pk2;   // P[q=lr][k], 8B aligned
    }
    __builtin_amdgcn_wave_barrier();
    asm volatile("s_waitcnt lgkmcnt(0)" ::: "memory");
    bf16x8 ap0 = *(const bf16x8*)&Pw[lr*PADP + lg*8];
    bf16x8 ap1 = *(const bf16x8*)&Pw[lr*PADP + 32 + lg*8];
    #pragma unroll
    for (int nf=0;nf<4;nf++){
      int row = nf*16 + lr;
      int sw0 = ((lg    ) ^ (row&7))*8;
      int sw1 = ((4 | lg) ^ (row&7))*8;
      accY[nf] = __builtin_amdgcn_mfma_f32_16x16x32_bf16(ap0, *(const bf16x8*)&Vc[row*64 + sw0], accY[nf], 0,0,0);
      accY[nf] = __builtin_amdgcn_mfma_f32_16x16x32_bf16(ap1, *(const bf16x8*)&Vc[row*64 + sw1], accY[nf], 0,0,0);
    }
    __builtin_amdgcn_s_setprio(0);
    __syncthreads();                   // drains prefetch + guards shared K/V buffer reuse
    cur ^= 1;
  }
  #pragma unroll
  for (int nf=0;nf<4;nf++)
    #pragma unroll
    for (int rr=0;rr<4;rr++)
      Y[(base + qg0 + lg*4 + rr)*C + hh*64 + nf*16 + lr] = f2bf(accY[nf][rr]);
}

extern "C" void kernel_launch(void* const* d_in, const int* in_sizes, int n_in,
                              void* d_out, int out_size, void* d_ws, size_t ws_size,
                              hipStream_t stream)
{
  (void)in_sizes; (void)n_in; (void)out_size; (void)ws_size;
  const float* x      = (const float*)d_in[0];
  const float* w_ln1  = (const float*)d_in[1];
  const float* w_attn = (const float*)d_in[2];
  const float* w_ap   = (const float*)d_in[3];
  const float* w_ln2  = (const float*)d_in[4];
  const float* w_fc   = (const float*)d_in[5];
  const float* w_mlp  = (const float*)d_in[6];
  float* out = (float*)d_out;
  const int M = 4096, T = 2048;   // B=2, T=2048, C=768
  const long NROW = (long)M*768;

  u16* ws      = (u16*)d_ws;
  u16* wT_attn = ws;                        // 2304*768
  u16* wT_ap   = wT_attn + 2304*768;        // 768*768
  u16* wT_fc   = wT_ap   + 768*768;         // 3072*768
  u16* wT_mlp  = wT_fc   + 3072*768;        // 768*3072
  u16* xln     = wT_mlp  + 768*3072;        // 4096*768
  u16* qkvb    = xln     + 4096*768;        // 4096*2304
  u16* Ybuf    = qkvb    + 4096*2304;       // 4096*768
  u16* hbuf    = qkvb;                      // 4096*3072 aliases qkv|Ybuf (exact fit)
  float* x2    = (float*)(Ybuf + 4096*768); // 4096*768 fp32
  u16* vtb     = (u16*)(x2 + 4096*768);     // 2*12*64*2048
  float* q2g   = (float*)(vtb + 2*12*64*2048); // 24*2048
  float* k2g   = q2g + 24*2048;                // 24*2048
  float* pbuf  = k2g + 24*2048;                // 2 * 4096*768 fp32 (split-K partials)

  dim3 blk(256);
  transpose_cast<<<dim3(2304/32,  768/32), blk, 0, stream>>>(w_attn, wT_attn,  768, 2304);
  transpose_cast<<<dim3( 768/32,  768/32), blk, 0, stream>>>(w_ap,   wT_ap,    768,  768);
  transpose_cast<<<dim3(3072/32,  768/32), blk, 0, stream>>>(w_fc,   wT_fc,    768, 3072);
  transpose_cast<<<dim3( 768/32, 3072/32), blk, 0, stream>>>(w_mlp,  wT_mlp,  3072,  768);

  ln_rows<<<dim3(M), blk, 0, stream>>>(x, w_ln1, xln);
  gemm_bt<0><<<dim3(2304/128, M/128), blk, 0, stream>>>(xln, wT_attn, M, 2304, 768, qkvb, q2g, k2g);
  v_transpose<<<dim3(T/64, 12, 2), blk, 0, stream>>>(qkvb, vtb);
  attn_fused<<<dim3(2*12*64), dim3(128), 0, stream>>>(qkvb, vtb, q2g, k2g, Ybuf);
  gemm_ks<<<dim3(768/64, M/128, 2), blk, 0, stream>>>(Ybuf, wT_ap, M, 768, 768, 384, pbuf);
  reduce2_ln<<<dim3(M), blk, 0, stream>>>(pbuf, x, w_ln2, x2, xln, NROW);
  gemm_bt<1><<<dim3(3072/128, M/128), blk, 0, stream>>>(xln, wT_fc, M, 3072, 768, hbuf, nullptr, nullptr);
  gemm_ks<<<dim3(768/64, M/128, 2), blk, 0, stream>>>(hbuf, wT_mlp, M, 768, 3072, 1536, pbuf);
  reduce2<<<dim3(NROW/1024), blk, 0, stream>>>(pbuf, x2, out, NROW);
}